// Round 1
// baseline (816.023 us; speedup 1.0000x reference)
//
#include <hip/hip_runtime.h>

#define SEQ_LEN 96
#define PRED_LEN 16
#define HIDDEN 64
#define FEAT 7
#define BATCH 512
#define TL (SEQ_LEN + PRED_LEN)   // 112-row sliding timeline
#define XSTR 8                    // padded row stride; col 7 == 1.0 (bias lane)

typedef float v2f __attribute__((ext_vector_type(2)));

#define L2E 1.4426950408889634f

// DPP quad swaps. Pure VALU, quad-aligned since quad = (unit u, gates 0..3).
__device__ __forceinline__ float qp_xor1(float v) {  // [1,0,3,2]
    return __int_as_float(__builtin_amdgcn_mov_dpp(__float_as_int(v), 0xB1, 0xF, 0xF, true));
}
__device__ __forceinline__ float qp_xor2(float v) {  // [2,3,0,1]
    return __int_as_float(__builtin_amdgcn_mov_dpp(__float_as_int(v), 0x4E, 0xF, 0xF, true));
}

struct X2 { float4 a, b; };

// r10 redesign: (unit, gate) per thread.
//  - 256 threads/block (4 waves) = ONE batch element; thread (u=tid>>2, g=tid&3)
//    owns the FULL K=64 dot of gate g of unit u -> 64 weight floats/thread.
//    Fits arch VGPRs: kills the AGPR demotion + ~130 copies/step that capped r7-r9
//    (VGPR_Count=132 evidence; ~2.4x VALU inflation at 58% busy).
//  - No cross-lane K-reduce. Only the i/f/g/o exchange: 3 quad-perm DPPs.
//    Lane g==0 assembles the true (i,f,g,o) with ZERO selects; lanes 1-3 run a
//    garbage-but-bounded c-chain and write to a scratch sink via a PREcomputed
//    address (no divergence, no per-step select).
//  - All h reads are wave-uniform float4 broadcasts -> bank-conflict-free.
//  - Bias folded into x col 7 (timeline col 7 held at 1.0f; wx[3].y = b_ih+b_hh).
//  - grid 512 -> 2 independent blocks/CU (staggered barriers, r8 lesson),
//    2 waves/SIMD to hide the per-step recurrence tail. launch_bounds(256,2)
//    budgets 256 VGPRs/wave.
__global__ __launch_bounds__(256, 2)
void lstm_ar_kernel(
    const float* __restrict__ x,     // [B, 96, 7]
    const float* __restrict__ W_ih,  // [256, 7]
    const float* __restrict__ W_hh,  // [256, 64]
    const float* __restrict__ b_ih,  // [256]
    const float* __restrict__ b_hh,  // [256]
    const float* __restrict__ fc_W,  // [7, 64]
    const float* __restrict__ fc_b,  // [7]
    float* __restrict__ out)         // [B, 16, 7]
{
    __shared__ float xs[TL * XSTR];   // sliding timeline, col7 = 1.0
    __shared__ float hb0[HIDDEN];     // h ping-pong
    __shared__ float hb1[HIDDEN];
    __shared__ float hscr[64];        // garbage-h sink (never read)
    __shared__ float fcw[FEAT * HIDDEN];
    __shared__ float fcb[FEAT];

    const int tid = threadIdx.x;
    const int b   = blockIdx.x;
    const int u   = tid >> 2;         // hidden unit 0..63
    const int g   = tid & 3;          // gate 0..3 = i,f,g,o (PyTorch order)
    const int row = (g << 6) + u;     // W row

    // ---- per-thread weights: one gate, all 64 K-cols ----
    v2f wh[32];
    {
        const float* wr = W_hh + row * HIDDEN;
        #pragma unroll
        for (int j = 0; j < 32; ++j) wh[j] = *(const v2f*)(wr + 2 * j);
    }
    v2f wx[4];                        // x cols 0..6 + bias in slot 7
    #pragma unroll
    for (int i = 0; i < 4; ++i) {
        int c0 = 2 * i, c1 = 2 * i + 1;
        wx[i].x = W_ih[row * FEAT + c0];
        wx[i].y = (c1 < FEAT) ? W_ih[row * FEAT + c1]
                              : (b_ih[row] + b_hh[row]);   // pairs with xs col7==1.0
    }

    // activation constants: gate 2 is tanh, others sigmoid
    const float bk  = (g == 2) ? (-2.0f * L2E) : (-L2E);
    const float bm  = (g == 2) ? 2.0f : 1.0f;
    const float bbc = (g == 2) ? -1.0f : 0.0f;

    // precomputed h-write addresses: real for g==0, scratch sink otherwise
    float* const wa1 = (g == 0) ? (hb1 + u) : (hscr + (tid & 63));
    float* const wa0 = (g == 0) ? (hb0 + u) : (hscr + (tid & 63));

    // ---- stage timeline / fc / init ----
    for (int i = tid; i < TL * XSTR; i += 256) {
        int r = i >> 3, f = i & 7;
        float v = 1.0f;                                    // col 7 = bias input
        if (f < FEAT) v = (r < SEQ_LEN) ? x[b * SEQ_LEN * FEAT + r * FEAT + f] : 0.0f;
        xs[i] = v;
    }
    for (int i = tid; i < FEAT * HIDDEN; i += 256) fcw[i] = fc_W[i];
    if (tid < FEAT)   fcb[tid] = fc_b[tid];
    if (tid < HIDDEN) hb0[tid] = 0.0f;
    float c = 0.0f;                   // real only in g==0 lanes; bounded garbage elsewhere
    __syncthreads();

    // One step: consumes prefetched x row, reads hr (broadcast), writes h,
    // prefetches row `nrow` in the barrier shadow. ONE barrier per step.
    auto step = [&](X2 xv, int nrow, const float* __restrict__ hr,
                    float* __restrict__ wa) -> X2 {
        v2f xl0; xl0.x = xv.a.x; xl0.y = xv.a.y;
        v2f xl1; xl1.x = xv.a.z; xl1.y = xv.a.w;
        v2f xh0; xh0.x = xv.b.x; xh0.y = xv.b.y;
        v2f xh1; xh1.x = xv.b.z; xh1.y = xv.b.w;   // {col6, 1.0}
        v2f A0 = wx[0] * xl0;                      // bias rides in via wx[3].y*1.0
        v2f A1 = wx[1] * xl1;
        v2f A2 = wx[2] * xh0;
        v2f A3 = wx[3] * xh1;

        const float4* h4 = (const float4*)hr;      // same addr across wave: broadcast
        #pragma unroll
        for (int j = 0; j < 16; j += 2) {          // 4 chains of depth 8
            float4 h0 = h4[j];
            float4 h1 = h4[j + 1];
            v2f l0; l0.x = h0.x; l0.y = h0.y;
            v2f i0; i0.x = h0.z; i0.y = h0.w;
            v2f l1; l1.x = h1.x; l1.y = h1.y;
            v2f i1; i1.x = h1.z; i1.y = h1.w;
            A0 = __builtin_elementwise_fma(wh[2 * j],     l0, A0);
            A1 = __builtin_elementwise_fma(wh[2 * j + 1], i0, A1);
            A2 = __builtin_elementwise_fma(wh[2 * j + 2], l1, A2);
            A3 = __builtin_elementwise_fma(wh[2 * j + 3], i1, A3);
        }
        A0 = A0 + A2;
        A1 = A1 + A3;
        A0 = A0 + A1;
        float r = A0.x + A0.y;                     // full preactivation of gate g

        // activate own gate
        float e   = __builtin_amdgcn_exp2f(r * bk);
        float rc  = __builtin_amdgcn_rcpf(1.0f + e);
        float act = fmaf(bm, rc, bbc);

        // quad exchange: lane g==0 sees act=i, p1=f, p2=g, p3=o (zero selects)
        float p1 = qp_xor1(act);
        float p2 = qp_xor2(act);
        float p3 = qp_xor2(p1);

        c = fmaf(p1, c, act * p2);                 // c = f*c + i*g
        float e2 = __builtin_amdgcn_exp2f(c * (-2.0f * L2E));
        float rr = __builtin_amdgcn_rcpf(1.0f + e2);
        float th = fmaf(2.0f, rr, -1.0f);          // tanh(c)
        *wa = p3 * th;                             // h = o*tanh(c); g!=0 -> scratch

        // prefetch next x row in the barrier shadow
        const float4* nx = (const float4*)(xs + nrow * XSTR);
        X2 nxt; nxt.a = nx[0]; nxt.b = nx[1];
        __syncthreads();
        return nxt;
    };

    for (int k = 0; k < PRED_LEN; ++k) {
        const float4* x0 = (const float4*)(xs + k * XSTR);
        X2 cur; cur.a = x0[0]; cur.b = x0[1];
        for (int t = 0; t < SEQ_LEN; t += 2) {
            cur = step(cur, k + t + 1, hb0, wa1);
            cur = step(cur, k + t + 2, hb1, wa0);  // t=94: prefetch row k+96 (stale, discarded)
        }
        // after 96 steps latest h is in hb0

        // ---- prediction head: lanes 0..6 of wave 0 ----
        if (tid < FEAT) {
            float p0 = fcb[tid], p1 = 0.0f, p2 = 0.0f, p3 = 0.0f;
            const float4* hh = (const float4*)hb0;
            #pragma unroll
            for (int j = 0; j < 16; ++j) {
                float4 hv = hh[j];
                p0 = fmaf(fcw[tid * HIDDEN + 4 * j + 0], hv.x, p0);
                p1 = fmaf(fcw[tid * HIDDEN + 4 * j + 1], hv.y, p1);
                p2 = fmaf(fcw[tid * HIDDEN + 4 * j + 2], hv.z, p2);
                p3 = fmaf(fcw[tid * HIDDEN + 4 * j + 3], hv.w, p3);
            }
            float pred = (p0 + p1) + (p2 + p3);
            out[(b * PRED_LEN + k) * FEAT + tid] = pred;
            xs[(SEQ_LEN + k) * XSTR + tid] = pred; // append; col7 stays 1.0
        }
        __syncthreads();
    }
}

extern "C" void kernel_launch(void* const* d_in, const int* in_sizes, int n_in,
                              void* d_out, int out_size, void* d_ws, size_t ws_size,
                              hipStream_t stream) {
    const float* x    = (const float*)d_in[0];
    const float* W_ih = (const float*)d_in[1];
    const float* W_hh = (const float*)d_in[2];
    const float* b_ih = (const float*)d_in[3];
    const float* b_hh = (const float*)d_in[4];
    const float* fc_W = (const float*)d_in[5];
    const float* fc_b = (const float*)d_in[6];
    float* out = (float*)d_out;

    lstm_ar_kernel<<<BATCH, 256, 0, stream>>>(x, W_ih, W_hh, b_ih, b_hh, fc_W, fc_b, out);
}

// Round 2
// 552.261 us; speedup vs baseline: 1.4776x; 1.4776x over previous
//
#include <hip/hip_runtime.h>

#define SEQ_LEN 96
#define PRED_LEN 16
#define HIDDEN 64
#define FEAT 7
#define BATCH 512
#define TL (SEQ_LEN + PRED_LEN)   // 112-row sliding timeline
#define XSTR 8                    // padded row stride; col 7 == 1.0 (bias lane)

typedef float v2f __attribute__((ext_vector_type(2)));

#define L2E 1.4426950408889634f

// DPP quad ops (pure VALU). Quad = the 4 lanes of one hidden unit.
__device__ __forceinline__ float qp_xor1(float v) {  // [1,0,3,2]
    return __int_as_float(__builtin_amdgcn_mov_dpp(__float_as_int(v), 0xB1, 0xF, 0xF, true));
}
__device__ __forceinline__ float qp_xor2(float v) {  // [2,3,0,1]
    return __int_as_float(__builtin_amdgcn_mov_dpp(__float_as_int(v), 0x4E, 0xF, 0xF, true));
}
__device__ __forceinline__ float qp_rot1(float v) {  // lane q <- lane (q+1)&3 : [1,2,3,0]
    return __int_as_float(__builtin_amdgcn_mov_dpp(__float_as_int(v), 0x39, 0xF, 0xF, true));
}
__device__ __forceinline__ float qp_rot3(float v) {  // lane q <- lane (q+3)&3 : [3,0,1,2]
    return __int_as_float(__builtin_amdgcn_mov_dpp(__float_as_int(v), 0x93, 0xF, 0xF, true));
}

// r11: thread = (unit u = tid>>2, K-quarter q = tid&3), ALL 4 gates per lane.
//  - r10 post-mortem: (unit,gate)/thread made every lane read the full 256B of
//    h per step (1x reuse) -> 64KB/block-step of LDS return traffic -> ~1024
//    cyc/CU/step, LDS-BW bound (VALUBusy fell to 39%). Return BW is per-lane
//    even for broadcasts; traffic = threads x K-span x 4B, reuse = rows/lane.
//  - This layout: 64 weight floats/lane (4 gates x 16 K) -> fits arch VGPRs
//    (~120 total, under the 132 demotion cap r7 hit with 128 weight floats),
//    AND 4x h reuse -> 16KB/block-step (~300 LDS cyc/CU/step).
//  - Accumulator k of lane q holds gate (q+k)&3, so a 3-step DPP ROTATION
//    reduce leaves lane q with the FULL preactivation of gate q (partials of
//    gate q live at index 3,2,1 in lanes q+1,q+2,q+3). Lane q activates only
//    its own gate; 3 DPP xors share (i,f,g,o); c-chain redundant per quad
//    (garbage-but-bounded in q!=0 lanes, r10-proven).
//  - Sink writes laid out so each wave's 64 stores hit every bank exactly
//    twice (2-way = free on CDNA4).
//  - Bias folded into x col 7 (==1.0), carried by q==3's wx[k].y.
//  - grid 512 x 256 thr -> 2 blocks/CU, staggered barriers, 2 waves/SIMD.
__global__ __launch_bounds__(256)
__attribute__((amdgpu_waves_per_eu(2)))
void lstm_ar_kernel(
    const float* __restrict__ x,     // [B, 96, 7]
    const float* __restrict__ W_ih,  // [256, 7]
    const float* __restrict__ W_hh,  // [256, 64]
    const float* __restrict__ b_ih,  // [256]
    const float* __restrict__ b_hh,  // [256]
    const float* __restrict__ fc_W,  // [7, 64]
    const float* __restrict__ fc_b,  // [7]
    float* __restrict__ out)         // [B, 16, 7]
{
    __shared__ float xs[TL * XSTR];   // sliding timeline, col7 = 1.0
    __shared__ float hb0[HIDDEN];     // h ping-pong (bank-0 aligned)
    __shared__ float hb1[HIDDEN];
    __shared__ float hscr[HIDDEN];    // garbage-h sink (never read)
    __shared__ float fcw[FEAT * HIDDEN];
    __shared__ float fcb[FEAT];

    const int tid = threadIdx.x;
    const int b   = blockIdx.x;
    const int u   = tid >> 2;         // hidden unit 0..63
    const int q   = tid & 3;          // K-quarter 0..3, also "own gate" id

    // ---- per-thread weights: 4 gates x K-quarter [16q,16q+16) ----
    // accumulator k holds gate (q+k)&3  (rotated layout for the DPP reduce)
    v2f wh[4][8];
    #pragma unroll
    for (int k = 0; k < 4; ++k) {
        const int gate = (q + k) & 3;
        const float* wr = W_hh + ((gate << 6) + u) * HIDDEN + (q << 4);
        #pragma unroll
        for (int j = 0; j < 8; ++j) wh[k][j] = *(const v2f*)(wr + 2 * j);
    }
    v2f wx[4];                        // x cols [2q, 2q+2); q==3 pairs col6 with bias
    #pragma unroll
    for (int k = 0; k < 4; ++k) {
        const int gate = (q + k) & 3;
        const int row  = (gate << 6) + u;
        const int c0 = (q << 1), c1 = c0 + 1;
        wx[k].x = W_ih[row * FEAT + c0];
        wx[k].y = (c1 < FEAT) ? W_ih[row * FEAT + c1]
                              : (b_ih[row] + b_hh[row]);   // pairs with xs col7==1.0
    }

    // activation constants: lane q activates gate q; gate 2 is tanh
    const float bk  = (q == 2) ? (-2.0f * L2E) : (-L2E);
    const float bm  = (q == 2) ? 2.0f : 1.0f;
    const float bbc = (q == 2) ? -1.0f : 0.0f;

    // h-write pointers: real for q==0; sink slots (u+16q)&63 give every wave a
    // perfect 2-per-bank store pattern (real bank u, sink banks paired)
    float* const sink = hscr + ((u + (q << 4)) & 63);
    float* const wa1 = (q == 0) ? (hb1 + u) : sink;
    float* const wa0 = (q == 0) ? (hb0 + u) : sink;

    // per-lane h-read base: K-quarter q => 4 float4s at hb + 16q
    const float4* const h40 = (const float4*)(hb0 + (q << 4));
    const float4* const h41 = (const float4*)(hb1 + (q << 4));
    const float* const xq = xs + (q << 1);   // this lane's 2 x-cols

    // ---- stage timeline / fc / init ----
    for (int i = tid; i < TL * XSTR; i += 256) {
        int r = i >> 3, f = i & 7;
        float v = 1.0f;                                    // col 7 = bias input
        if (f < FEAT) v = (r < SEQ_LEN) ? x[b * SEQ_LEN * FEAT + r * FEAT + f] : 0.0f;
        xs[i] = v;
    }
    for (int i = tid; i < FEAT * HIDDEN; i += 256) fcw[i] = fc_W[i];
    if (tid < FEAT)   fcb[tid] = fc_b[tid];
    if (tid < HIDDEN) hb0[tid] = 0.0f;
    float c = 0.0f;                   // real only in q==0 lanes; bounded garbage elsewhere
    __syncthreads();

    // One step: consumes prefetched x pair, reads h quarter (4x b128), rotation-
    // reduces across the quad, activates own gate, shares via DPP, writes h,
    // prefetches x row `nrow` in the barrier shadow. ONE barrier per step.
    auto step = [&](v2f xv, int nrow, const float4* __restrict__ h4,
                    float* __restrict__ wa) -> v2f {
        v2f A0 = wx[0] * xv;          // bias rides in via q==3's wx[k].y * 1.0
        v2f A1 = wx[1] * xv;
        v2f A2 = wx[2] * xv;
        v2f A3 = wx[3] * xv;

        #pragma unroll
        for (int j = 0; j < 4; ++j) {                 // 16 h values, 4x reuse
            float4 hv = h4[j];
            v2f lo; lo.x = hv.x; lo.y = hv.y;
            v2f hi; hi.x = hv.z; hi.y = hv.w;
            A0 = __builtin_elementwise_fma(wh[0][2*j],   lo, A0);
            A1 = __builtin_elementwise_fma(wh[1][2*j],   lo, A1);
            A2 = __builtin_elementwise_fma(wh[2][2*j],   lo, A2);
            A3 = __builtin_elementwise_fma(wh[3][2*j],   lo, A3);
            A0 = __builtin_elementwise_fma(wh[0][2*j+1], hi, A0);
            A1 = __builtin_elementwise_fma(wh[1][2*j+1], hi, A1);
            A2 = __builtin_elementwise_fma(wh[2][2*j+1], hi, A2);
            A3 = __builtin_elementwise_fma(wh[3][2*j+1], hi, A3);
        }

        // horizontal, then rotation-reduce: lane q gathers gate q's partials
        // (lane q+d holds gate q at accumulator index (4-d)&3)
        float r0 = A0.x + A0.y;       // own partial of gate q
        float r1 = A1.x + A1.y;       // gate q+1
        float r2 = A2.x + A2.y;       // gate q+2
        float r3 = A3.x + A3.y;       // gate q+3
        float sum = r0 + qp_rot1(r3);
        sum += qp_xor2(r2);           // rot2 == xor2
        sum += qp_rot3(r1);

        // activate own gate (q==2 -> tanh, else sigmoid)
        float e   = __builtin_amdgcn_exp2f(sum * bk);
        float rc  = __builtin_amdgcn_rcpf(1.0f + e);
        float a   = fmaf(bm, rc, bbc);

        // quad share: lane 0 sees a=i, p1=f, p2=g, p3=o (zero selects)
        float p1 = qp_xor1(a);
        float p2 = qp_xor2(a);
        float p3 = qp_xor2(p1);

        c = fmaf(p1, c, a * p2);                      // c = f*c + i*g
        float e2 = __builtin_amdgcn_exp2f(c * (-2.0f * L2E));
        float rr = __builtin_amdgcn_rcpf(1.0f + e2);
        float th = fmaf(2.0f, rr, -1.0f);             // tanh(c)
        *wa = p3 * th;                                // h = o*tanh(c); q!=0 -> sink

        // prefetch next x pair in the barrier shadow
        v2f nxt = *(const v2f*)(xq + nrow * XSTR);
        __syncthreads();              // the ONLY barrier per step
        return nxt;
    };

    for (int k = 0; k < PRED_LEN; ++k) {
        v2f cur = *(const v2f*)(xq + k * XSTR);       // row k (t=0)
        for (int t = 0; t < SEQ_LEN; t += 2) {
            cur = step(cur, k + t + 1, h40, wa1);
            cur = step(cur, k + t + 2, h41, wa0);     // t=94: prefetch row k+96 (stale, discarded)
        }
        // after 96 steps the latest h is in hb0

        // ---- prediction head: lanes 0..6 of wave 0 ----
        if (tid < FEAT) {
            float p0 = fcb[tid], p1 = 0.0f, p2 = 0.0f, p3 = 0.0f;
            const float4* hh = (const float4*)hb0;
            #pragma unroll
            for (int j = 0; j < 16; ++j) {
                float4 hv = hh[j];
                p0 = fmaf(fcw[tid * HIDDEN + 4 * j + 0], hv.x, p0);
                p1 = fmaf(fcw[tid * HIDDEN + 4 * j + 1], hv.y, p1);
                p2 = fmaf(fcw[tid * HIDDEN + 4 * j + 2], hv.z, p2);
                p3 = fmaf(fcw[tid * HIDDEN + 4 * j + 3], hv.w, p3);
            }
            float pred = (p0 + p1) + (p2 + p3);
            out[(b * PRED_LEN + k) * FEAT + tid] = pred;
            xs[(SEQ_LEN + k) * XSTR + tid] = pred;    // append; col7 stays 1.0
        }
        __syncthreads();
    }
}

extern "C" void kernel_launch(void* const* d_in, const int* in_sizes, int n_in,
                              void* d_out, int out_size, void* d_ws, size_t ws_size,
                              hipStream_t stream) {
    const float* x    = (const float*)d_in[0];
    const float* W_ih = (const float*)d_in[1];
    const float* W_hh = (const float*)d_in[2];
    const float* b_ih = (const float*)d_in[3];
    const float* b_hh = (const float*)d_in[4];
    const float* fc_W = (const float*)d_in[5];
    const float* fc_b = (const float*)d_in[6];
    float* out = (float*)d_out;

    lstm_ar_kernel<<<BATCH, 256, 0, stream>>>(x, W_ih, W_hh, b_ih, b_hh, fc_W, fc_b, out);
}

// Round 3
// 551.286 us; speedup vs baseline: 1.4802x; 1.0018x over previous
//
#include <hip/hip_runtime.h>

#define SEQ_LEN 96
#define PRED_LEN 16
#define HIDDEN 64
#define FEAT 7
#define BATCH 512
#define TL (SEQ_LEN + PRED_LEN)   // 112-row sliding timeline
#define XSTR 8                    // padded row stride; col 7 == 1.0 (bias lane)

typedef float v2f __attribute__((ext_vector_type(2)));

#define L2E 1.4426950408889634f

// DPP quad ops (pure VALU). Quad = the 4 lanes of one hidden unit.
__device__ __forceinline__ float qp_xor1(float v) {  // [1,0,3,2]
    return __int_as_float(__builtin_amdgcn_mov_dpp(__float_as_int(v), 0xB1, 0xF, 0xF, true));
}
__device__ __forceinline__ float qp_xor2(float v) {  // [2,3,0,1]
    return __int_as_float(__builtin_amdgcn_mov_dpp(__float_as_int(v), 0x4E, 0xF, 0xF, true));
}
__device__ __forceinline__ float qp_rot1(float v) {  // lane q <- lane (q+1)&3 : [1,2,3,0]
    return __int_as_float(__builtin_amdgcn_mov_dpp(__float_as_int(v), 0x39, 0xF, 0xF, true));
}
__device__ __forceinline__ float qp_rot3(float v) {  // lane q <- lane (q+3)&3 : [3,0,1,2]
    return __int_as_float(__builtin_amdgcn_mov_dpp(__float_as_int(v), 0x93, 0xF, 0xF, true));
}

// r12 = r11 structure + allocator fixes.
//  r11 post-mortem: VGPR_Count=64 -- the 64-float weight set CANNOT be resident
//  in 64 regs. amdgpu_waves_per_eu(2) set only a MIN; the allocator targeted
//  8 waves/EU, capped at 64 VGPRs, and rematerialized the weights every step
//  (L2-hit reloads / AGPR copies -- invisible in FETCH_SIZE). Measured
//  ~137 insts/wave-step vs ~58 hand-counted = 2.4x remat tax. Same failure as
//  r7 (132) and r10 (60). Fixes:
//   1. amdgpu_waves_per_eu(2,2): pin min AND max -> 256-reg budget/wave.
//      Grid already gives exactly 2 waves/SIMD (2 staggered blocks/CU x 4
//      waves), so the pin costs nothing.
//   2. asm-anchor the weight regs after load ("+v" no-op): breaks the SSA
//      link to the loads, making remat-by-reload illegal.
//  Decomposition (unchanged from r11): thread = (unit u = tid>>2, K-quarter
//  q = tid&3), all 4 gates per lane; 4x h reuse (16KB/block-step LDS);
//  rotation-reduce leaves lane q holding gate q's full preactivation;
//  3 DPP xors share (i,f,g,o); redundant c-chain per quad; sink writes 2-way.
__global__ __launch_bounds__(256)
__attribute__((amdgpu_waves_per_eu(2, 2)))
void lstm_ar_kernel(
    const float* __restrict__ x,     // [B, 96, 7]
    const float* __restrict__ W_ih,  // [256, 7]
    const float* __restrict__ W_hh,  // [256, 64]
    const float* __restrict__ b_ih,  // [256]
    const float* __restrict__ b_hh,  // [256]
    const float* __restrict__ fc_W,  // [7, 64]
    const float* __restrict__ fc_b,  // [7]
    float* __restrict__ out)         // [B, 16, 7]
{
    __shared__ float xs[TL * XSTR];   // sliding timeline, col7 = 1.0
    __shared__ float hb0[HIDDEN];     // h ping-pong
    __shared__ float hb1[HIDDEN];
    __shared__ float hscr[HIDDEN];    // garbage-h sink (never read)
    __shared__ float fcw[FEAT * HIDDEN];
    __shared__ float fcb[FEAT];

    const int tid = threadIdx.x;
    const int b   = blockIdx.x;
    const int u   = tid >> 2;         // hidden unit 0..63
    const int q   = tid & 3;          // K-quarter 0..3, also "own gate" id

    // ---- per-thread weights: 4 gates x K-quarter [16q,16q+16) ----
    // accumulator k holds gate (q+k)&3  (rotated layout for the DPP reduce)
    v2f wh[4][8];
    #pragma unroll
    for (int k = 0; k < 4; ++k) {
        const int gate = (q + k) & 3;
        const float* wr = W_hh + ((gate << 6) + u) * HIDDEN + (q << 4);
        #pragma unroll
        for (int j = 0; j < 8; ++j) wh[k][j] = *(const v2f*)(wr + 2 * j);
    }
    v2f wx[4];                        // x cols [2q, 2q+2); q==3 pairs col6 with bias
    #pragma unroll
    for (int k = 0; k < 4; ++k) {
        const int gate = (q + k) & 3;
        const int row  = (gate << 6) + u;
        const int c0 = (q << 1), c1 = c0 + 1;
        wx[k].x = W_ih[row * FEAT + c0];
        wx[k].y = (c1 < FEAT) ? W_ih[row * FEAT + c1]
                              : (b_ih[row] + b_hh[row]);   // pairs with xs col7==1.0
    }

    // ---- anchor weights in arch VGPRs: no-op asm breaks remat-by-reload ----
    #pragma unroll
    for (int k = 0; k < 4; ++k)
        #pragma unroll
        for (int j = 0; j < 8; ++j) {
            float t0 = wh[k][j].x, t1 = wh[k][j].y;
            asm volatile("" : "+v"(t0), "+v"(t1));
            wh[k][j].x = t0; wh[k][j].y = t1;
        }
    #pragma unroll
    for (int k = 0; k < 4; ++k) {
        float t0 = wx[k].x, t1 = wx[k].y;
        asm volatile("" : "+v"(t0), "+v"(t1));
        wx[k].x = t0; wx[k].y = t1;
    }

    // activation constants: lane q activates gate q; gate 2 is tanh
    const float bk  = (q == 2) ? (-2.0f * L2E) : (-L2E);
    const float bm  = (q == 2) ? 2.0f : 1.0f;
    const float bbc = (q == 2) ? -1.0f : 0.0f;

    // h-write pointers: real for q==0; sink slots (u+16q)&63 give every wave a
    // perfect 2-per-bank store pattern
    float* const sink = hscr + ((u + (q << 4)) & 63);
    float* const wa1 = (q == 0) ? (hb1 + u) : sink;
    float* const wa0 = (q == 0) ? (hb0 + u) : sink;

    // per-lane h-read base: K-quarter q => 4 float4s at hb + 16q
    const float4* const h40 = (const float4*)(hb0 + (q << 4));
    const float4* const h41 = (const float4*)(hb1 + (q << 4));
    const float* const xq = xs + (q << 1);   // this lane's 2 x-cols

    // ---- stage timeline / fc / init ----
    for (int i = tid; i < TL * XSTR; i += 256) {
        int r = i >> 3, f = i & 7;
        float v = 1.0f;                                    // col 7 = bias input
        if (f < FEAT) v = (r < SEQ_LEN) ? x[b * SEQ_LEN * FEAT + r * FEAT + f] : 0.0f;
        xs[i] = v;
    }
    for (int i = tid; i < FEAT * HIDDEN; i += 256) fcw[i] = fc_W[i];
    if (tid < FEAT)   fcb[tid] = fc_b[tid];
    if (tid < HIDDEN) hb0[tid] = 0.0f;
    float c = 0.0f;                   // real only in q==0 lanes; bounded garbage elsewhere
    __syncthreads();

    // One step: consumes prefetched x pair, reads h quarter (4x b128), rotation-
    // reduces across the quad, activates own gate, shares via DPP, writes h,
    // prefetches x row `nrow` in the barrier shadow. ONE barrier per step.
    auto step = [&](v2f xv, int nrow, const float4* __restrict__ h4,
                    float* __restrict__ wa) -> v2f {
        v2f A0 = wx[0] * xv;          // bias rides in via q==3's wx[k].y * 1.0
        v2f A1 = wx[1] * xv;
        v2f A2 = wx[2] * xv;
        v2f A3 = wx[3] * xv;

        #pragma unroll
        for (int j = 0; j < 4; ++j) {                 // 16 h values, 4x reuse
            float4 hv = h4[j];
            v2f lo; lo.x = hv.x; lo.y = hv.y;
            v2f hi; hi.x = hv.z; hi.y = hv.w;
            A0 = __builtin_elementwise_fma(wh[0][2*j],   lo, A0);
            A1 = __builtin_elementwise_fma(wh[1][2*j],   lo, A1);
            A2 = __builtin_elementwise_fma(wh[2][2*j],   lo, A2);
            A3 = __builtin_elementwise_fma(wh[3][2*j],   lo, A3);
            A0 = __builtin_elementwise_fma(wh[0][2*j+1], hi, A0);
            A1 = __builtin_elementwise_fma(wh[1][2*j+1], hi, A1);
            A2 = __builtin_elementwise_fma(wh[2][2*j+1], hi, A2);
            A3 = __builtin_elementwise_fma(wh[3][2*j+1], hi, A3);
        }

        // horizontal, then rotation-reduce: lane q gathers gate q's partials
        // (lane q+d holds gate q at accumulator index (4-d)&3)
        float r0 = A0.x + A0.y;       // own partial of gate q
        float r1 = A1.x + A1.y;       // gate q+1
        float r2 = A2.x + A2.y;       // gate q+2
        float r3 = A3.x + A3.y;       // gate q+3
        float sum = r0 + qp_rot1(r3);
        sum += qp_xor2(r2);           // rot2 == xor2
        sum += qp_rot3(r1);

        // activate own gate (q==2 -> tanh, else sigmoid)
        float e   = __builtin_amdgcn_exp2f(sum * bk);
        float rc  = __builtin_amdgcn_rcpf(1.0f + e);
        float a   = fmaf(bm, rc, bbc);

        // quad share: lane 0 sees a=i, p1=f, p2=g, p3=o (zero selects)
        float p1 = qp_xor1(a);
        float p2 = qp_xor2(a);
        float p3 = qp_xor2(p1);

        c = fmaf(p1, c, a * p2);                      // c = f*c + i*g
        float e2 = __builtin_amdgcn_exp2f(c * (-2.0f * L2E));
        float rr = __builtin_amdgcn_rcpf(1.0f + e2);
        float th = fmaf(2.0f, rr, -1.0f);             // tanh(c)
        *wa = p3 * th;                                // h = o*tanh(c); q!=0 -> sink

        // prefetch next x pair in the barrier shadow
        v2f nxt = *(const v2f*)(xq + nrow * XSTR);
        __syncthreads();              // the ONLY barrier per step
        return nxt;
    };

    for (int k = 0; k < PRED_LEN; ++k) {
        v2f cur = *(const v2f*)(xq + k * XSTR);       // row k (t=0)
        for (int t = 0; t < SEQ_LEN; t += 2) {
            cur = step(cur, k + t + 1, h40, wa1);
            cur = step(cur, k + t + 2, h41, wa0);     // t=94: prefetch row k+96 (stale, discarded)
        }
        // after 96 steps the latest h is in hb0

        // ---- prediction head: lanes 0..6 of wave 0 ----
        if (tid < FEAT) {
            float p0 = fcb[tid], p1 = 0.0f, p2 = 0.0f, p3 = 0.0f;
            const float4* hh = (const float4*)hb0;
            #pragma unroll
            for (int j = 0; j < 16; ++j) {
                float4 hv = hh[j];
                p0 = fmaf(fcw[tid * HIDDEN + 4 * j + 0], hv.x, p0);
                p1 = fmaf(fcw[tid * HIDDEN + 4 * j + 1], hv.y, p1);
                p2 = fmaf(fcw[tid * HIDDEN + 4 * j + 2], hv.z, p2);
                p3 = fmaf(fcw[tid * HIDDEN + 4 * j + 3], hv.w, p3);
            }
            float pred = (p0 + p1) + (p2 + p3);
            out[(b * PRED_LEN + k) * FEAT + tid] = pred;
            xs[(SEQ_LEN + k) * XSTR + tid] = pred;    // append; col7 stays 1.0
        }
        __syncthreads();
    }
}

extern "C" void kernel_launch(void* const* d_in, const int* in_sizes, int n_in,
                              void* d_out, int out_size, void* d_ws, size_t ws_size,
                              hipStream_t stream) {
    const float* x    = (const float*)d_in[0];
    const float* W_ih = (const float*)d_in[1];
    const float* W_hh = (const float*)d_in[2];
    const float* b_ih = (const float*)d_in[3];
    const float* b_hh = (const float*)d_in[4];
    const float* fc_W = (const float*)d_in[5];
    const float* fc_b = (const float*)d_in[6];
    float* out = (float*)d_out;

    lstm_ar_kernel<<<BATCH, 256, 0, stream>>>(x, W_ih, W_hh, b_ih, b_hh, fc_W, fc_b, out);
}